// Round 2
// baseline (357.587 us; speedup 1.0000x reference)
//
#include <hip/hip_runtime.h>
#include <hip/hip_bf16.h>
#include <cstdint>

#define SS 4096
#define DD 1024

typedef __attribute__((ext_vector_type(4))) float f32x4;
typedef __attribute__((ext_vector_type(8))) short bf16x8;

__device__ __forceinline__ float bf2f(unsigned short u) {
    union { unsigned int i; float f; } v; v.i = ((unsigned int)u) << 16; return v.f;
}
__device__ __forceinline__ unsigned short f2bf(float f) {
    union { float f; unsigned int i; } v; v.f = f;
    unsigned int r = v.i + 0x7fff + ((v.i >> 16) & 1);  // round-nearest-even
    return (unsigned short)(r >> 16);
}

// ---------------- elementwise fp32 -> bf16 ----------------
__global__ void cast_f32_bf16(const float* __restrict__ in, unsigned short* __restrict__ out, int n) {
    int i = (blockIdx.x * blockDim.x + threadIdx.x) * 4;
    if (i < n) {
        float4 v = *(const float4*)(in + i);
        ushort4 o;
        o.x = f2bf(v.x); o.y = f2bf(v.y); o.z = f2bf(v.z); o.w = f2bf(v.w);
        *(ushort4*)(out + i) = o;
    }
}

// ---------------- W [K][N] fp32  ->  Wt [N][K] bf16 (tiled transpose) ----------------
__global__ void transpose_w(const float* __restrict__ in, unsigned short* __restrict__ out) {
    __shared__ float tile[32][33];
    int tx = threadIdx.x, ty = threadIdx.y;           // (32, 8)
    int c0 = blockIdx.x * 32, r0 = blockIdx.y * 32;
#pragma unroll
    for (int i = 0; i < 4; ++i) {
        int r = r0 + ty + i * 8;
        tile[ty + i * 8][tx] = in[(size_t)r * DD + c0 + tx];
    }
    __syncthreads();
#pragma unroll
    for (int i = 0; i < 4; ++i) {
        int r = ty + i * 8;
        out[(size_t)(c0 + r) * DD + r0 + tx] = f2bf(tile[tx][r]);
    }
}

// ---------------- V [S][D] bf16, rowsum[S] -> Vst [D][S] bf16 = V^T / rowsum ----------------
__global__ void scale_transpose_v(const unsigned short* __restrict__ vin,
                                  const float* __restrict__ rowsum,
                                  unsigned short* __restrict__ out) {
    __shared__ float tile[32][33];
    int tx = threadIdx.x, ty = threadIdx.y;           // (32, 8)
    int d0 = blockIdx.x * 32, j0 = blockIdx.y * 32;
#pragma unroll
    for (int i = 0; i < 4; ++i) {
        int j = j0 + ty + i * 8;
        tile[ty + i * 8][tx] = bf2f(vin[(size_t)j * DD + d0 + tx]) * (1.0f / rowsum[j]);
    }
    __syncthreads();
#pragma unroll
    for (int i = 0; i < 4; ++i) {
        int d = ty + i * 8;
        out[(size_t)(d0 + d) * SS + j0 + tx] = f2bf(tile[tx][d]);
    }
}

// ---------------- m97-style bf16 GEMM: C[M,N] = A[M,K] @ Bt[N,K]^T ----------------
// MODE 0: C = acc + bias[col], store bf16
// MODE 1: C = exp(acc/1024), store bf16, atomicAdd row sums into rowsum[]
// MODE 2: C = acc, store fp32
template <int MODE>
__global__ __launch_bounds__(256) void gemm_bt(
        const unsigned short* __restrict__ A, const unsigned short* __restrict__ Bt,
        const float* __restrict__ bias, float* __restrict__ rowsum,
        void* __restrict__ Cout, int M, int N, int K) {
    __shared__ unsigned short As[128 * 32];
    __shared__ unsigned short Bs[128 * 32];

    const int t = threadIdx.x;
    const int l = t & 63;
    const int w = t >> 6;
    const int wm = w >> 1, wn = w & 1;      // 2x2 wave grid, each wave 64x64
    const int bm = blockIdx.y, bn = blockIdx.x;

    f32x4 acc[4][4] = {};

    const size_t a_base = (size_t)bm * 128 * K;
    const size_t b_base = (size_t)bn * 128 * K;
    const int lk = (l >> 4) * 8;            // k-offset within BK=32
    const int lr = l & 15;

    for (int k0 = 0; k0 < K; k0 += 32) {
        // async global -> LDS staging, 16B/lane, linear LDS layout [row][32]
#pragma unroll
        for (int i = 0; i < 2; ++i) {
            int idx = i * 256 + t;          // covers 8 bf16 each
            int row = idx >> 2;
            int col = (idx & 3) * 8;
            __builtin_amdgcn_global_load_lds(
                (const __attribute__((address_space(1))) void*)(A + a_base + (size_t)row * K + k0 + col),
                (__attribute__((address_space(3))) void*)(As + idx * 8), 16, 0, 0);
            __builtin_amdgcn_global_load_lds(
                (const __attribute__((address_space(1))) void*)(Bt + b_base + (size_t)row * K + k0 + col),
                (__attribute__((address_space(3))) void*)(Bs + idx * 8), 16, 0, 0);
        }
        __syncthreads();

        bf16x8 af[4], bfr[4];
#pragma unroll
        for (int m = 0; m < 4; ++m)
            af[m] = *(const bf16x8*)&As[(wm * 64 + m * 16 + lr) * 32 + lk];
#pragma unroll
        for (int n = 0; n < 4; ++n)
            bfr[n] = *(const bf16x8*)&Bs[(wn * 64 + n * 16 + lr) * 32 + lk];
#pragma unroll
        for (int m = 0; m < 4; ++m)
#pragma unroll
            for (int n = 0; n < 4; ++n)
                acc[m][n] = __builtin_amdgcn_mfma_f32_16x16x32_bf16(af[m], bfr[n], acc[m][n], 0, 0, 0);
        __syncthreads();
    }

    // epilogue: C/D layout col = lane&15, row = (lane>>4)*4 + r
    const int r0 = (l >> 4) * 4;
    const int cc = l & 15;
#pragma unroll
    for (int m = 0; m < 4; ++m) {
        const int growb = bm * 128 + wm * 64 + m * 16 + r0;
        if (MODE == 1) {
            float rs[4] = {0.f, 0.f, 0.f, 0.f};
#pragma unroll
            for (int n = 0; n < 4; ++n) {
                const int gcol = bn * 128 + wn * 64 + n * 16 + cc;
#pragma unroll
                for (int r = 0; r < 4; ++r) {
                    float e = __expf(acc[m][n][r] * (1.0f / 1024.0f));
                    rs[r] += e;
                    ((unsigned short*)Cout)[(size_t)(growb + r) * N + gcol] = f2bf(e);
                }
            }
#pragma unroll
            for (int r = 0; r < 4; ++r) {
                float v = rs[r];
                v += __shfl_xor(v, 1, 64);
                v += __shfl_xor(v, 2, 64);
                v += __shfl_xor(v, 4, 64);
                v += __shfl_xor(v, 8, 64);
                if (cc == 0) atomicAdd(&rowsum[growb + r], v);
            }
        } else {
#pragma unroll
            for (int n = 0; n < 4; ++n) {
                const int gcol = bn * 128 + wn * 64 + n * 16 + cc;
#pragma unroll
                for (int r = 0; r < 4; ++r) {
                    float v = acc[m][n][r];
                    if (MODE == 0) {
                        v += bias[gcol];
                        ((unsigned short*)Cout)[(size_t)(growb + r) * N + gcol] = f2bf(v);
                    } else {
                        ((float*)Cout)[(size_t)(growb + r) * N + gcol] = v;
                    }
                }
            }
        }
    }
}

extern "C" void kernel_launch(void* const* d_in, const int* in_sizes, int n_in,
                              void* d_out, int out_size, void* d_ws, size_t ws_size,
                              hipStream_t stream) {
    const float* query = (const float*)d_in[0];
    const float* key   = (const float*)d_in[1];
    const float* value = (const float*)d_in[2];
    const float* Wq    = (const float*)d_in[3];
    const float* bq    = (const float*)d_in[4];
    const float* Wk    = (const float*)d_in[5];
    const float* bk    = (const float*)d_in[6];
    const float* Wv    = (const float*)d_in[7];
    const float* bv    = (const float*)d_in[8];
    float* out = (float*)d_out;

    char* ws = (char*)d_ws;
    const size_t SD = (size_t)SS * DD;           // 4M elems
    const size_t DDsz = (size_t)DD * DD;         // 1M elems

    // phase-1 region [0, 32MB): X (24MB) + Wt (6MB); later overlaid by E (32MB)
    unsigned short* Xq  = (unsigned short*)ws;
    unsigned short* Xk  = Xq + SD;
    unsigned short* Xv  = Xk + SD;
    unsigned short* Wqt = Xv + SD;
    unsigned short* Wkt = Wqt + DDsz;
    unsigned short* Wvt = Wkt + DDsz;
    unsigned short* E   = (unsigned short*)ws;   // overlays X/W once they are dead
    unsigned short* Qb  = (unsigned short*)(ws + ((size_t)32 << 20));
    unsigned short* Kb  = Qb + SD;
    unsigned short* Vb  = Kb + SD;
    unsigned short* Vst = Vb + SD;
    float* rowsum = (float*)(ws + ((size_t)64 << 20));

    hipMemsetAsync(rowsum, 0, SS * sizeof(float), stream);

    const int nSD = SS * DD;
    cast_f32_bf16<<<nSD / 4 / 256, 256, 0, stream>>>(query, Xq, nSD);
    cast_f32_bf16<<<nSD / 4 / 256, 256, 0, stream>>>(key,   Xk, nSD);
    cast_f32_bf16<<<nSD / 4 / 256, 256, 0, stream>>>(value, Xv, nSD);

    dim3 tb(32, 8);
    transpose_w<<<dim3(32, 32), tb, 0, stream>>>(Wq, Wqt);
    transpose_w<<<dim3(32, 32), tb, 0, stream>>>(Wk, Wkt);
    transpose_w<<<dim3(32, 32), tb, 0, stream>>>(Wv, Wvt);

    dim3 g1(DD / 128, SS / 128);   // (8, 32)
    gemm_bt<0><<<g1, 256, 0, stream>>>(Xq, Wqt, bq, nullptr, Qb, SS, DD, DD);
    gemm_bt<0><<<g1, 256, 0, stream>>>(Xk, Wkt, bk, nullptr, Kb, SS, DD, DD);
    gemm_bt<0><<<g1, 256, 0, stream>>>(Xv, Wvt, bv, nullptr, Vb, SS, DD, DD);

    dim3 g2(SS / 128, SS / 128);   // (32, 32)
    gemm_bt<1><<<g2, 256, 0, stream>>>(Qb, Kb, nullptr, rowsum, E, SS, SS, DD);

    scale_transpose_v<<<dim3(DD / 32, SS / 32), tb, 0, stream>>>(Vb, rowsum, Vst);

    gemm_bt<2><<<g1, 256, 0, stream>>>(E, Vst, nullptr, nullptr, out, SS, DD, SS);
}

// Round 4
// 290.185 us; speedup vs baseline: 1.2323x; 1.2323x over previous
//
#include <hip/hip_runtime.h>
#include <hip/hip_bf16.h>
#include <cstdint>

#define SS 4096
#define DD 1024

typedef __attribute__((ext_vector_type(4))) float f32x4;
typedef __attribute__((ext_vector_type(8))) short bf16x8;

__device__ __forceinline__ float bf2f(unsigned short u) {
    union { unsigned int i; float f; } v; v.i = ((unsigned int)u) << 16; return v.f;
}
__device__ __forceinline__ unsigned short f2bf(float f) {
    union { float f; unsigned int i; } v; v.f = f;
    unsigned int r = v.i + 0x7fff + ((v.i >> 16) & 1);  // round-nearest-even
    return (unsigned short)(r >> 16);
}

// ---------------- batched fp32 -> bf16 cast (z selects tensor) ----------------
__global__ void cast3_f32_bf16(const float* __restrict__ q, const float* __restrict__ k,
                               const float* __restrict__ v,
                               unsigned short* __restrict__ oq, unsigned short* __restrict__ ok,
                               unsigned short* __restrict__ ov) {
    const int z = blockIdx.z;
    const float* in = (z == 0) ? q : (z == 1) ? k : v;
    unsigned short* out = (z == 0) ? oq : (z == 1) ? ok : ov;
    int i = (blockIdx.x * blockDim.x + threadIdx.x) * 4;
    float4 val = *(const float4*)(in + i);
    ushort4 o;
    o.x = f2bf(val.x); o.y = f2bf(val.y); o.z = f2bf(val.z); o.w = f2bf(val.w);
    *(ushort4*)(out + i) = o;
}

// ---------------- batched W [K][N] fp32 -> Wt [N][K] bf16 transpose ----------------
__global__ void transpose3_w(const float* __restrict__ wq, const float* __restrict__ wk,
                             const float* __restrict__ wv,
                             unsigned short* __restrict__ oq, unsigned short* __restrict__ ok,
                             unsigned short* __restrict__ ov) {
    const int z = blockIdx.z;
    const float* in = (z == 0) ? wq : (z == 1) ? wk : wv;
    unsigned short* out = (z == 0) ? oq : (z == 1) ? ok : ov;
    __shared__ float tile[32][33];
    int tx = threadIdx.x, ty = threadIdx.y;           // (32, 8)
    int c0 = blockIdx.x * 32, r0 = blockIdx.y * 32;
#pragma unroll
    for (int i = 0; i < 4; ++i) {
        int r = r0 + ty + i * 8;
        tile[ty + i * 8][tx] = in[(size_t)r * DD + c0 + tx];
    }
    __syncthreads();
#pragma unroll
    for (int i = 0; i < 4; ++i) {
        int r = ty + i * 8;
        out[(size_t)(c0 + r) * DD + r0 + tx] = f2bf(tile[tx][r]);
    }
}

// ---------------- V [S][D] bf16, rowsum[S] -> Vst [D][S] bf16 = V^T / rowsum ----------------
__global__ void scale_transpose_v(const unsigned short* __restrict__ vin,
                                  const float* __restrict__ rowsum,
                                  unsigned short* __restrict__ out) {
    __shared__ float tile[32][33];
    int tx = threadIdx.x, ty = threadIdx.y;           // (32, 8)
    int d0 = blockIdx.x * 32, j0 = blockIdx.y * 32;
#pragma unroll
    for (int i = 0; i < 4; ++i) {
        int j = j0 + ty + i * 8;
        tile[ty + i * 8][tx] = bf2f(vin[(size_t)j * DD + d0 + tx]) * (1.0f / rowsum[j]);
    }
    __syncthreads();
#pragma unroll
    for (int i = 0; i < 4; ++i) {
        int d = ty + i * 8;
        out[(size_t)(d0 + d) * SS + j0 + tx] = f2bf(tile[tx][d]);
    }
}

// ---------------- 2-phase double-buffered bf16 GEMM core ----------------
// C[128-tile] = A[M,K] @ Bt[N,K]^T over k in [k_begin, k_begin+k_len)
// MODE 0: C = acc + bias[col], store bf16
// MODE 1: C = exp(acc/1024), store bf16, atomicAdd row sums into rowsum[]
// MODE 3: atomicAdd fp32 into Cout (split-K partial)
template <int MODE>
__device__ __forceinline__ void gemm_core(
        const unsigned short* __restrict__ A, const unsigned short* __restrict__ Bt,
        const float* __restrict__ bias, float* __restrict__ rowsum,
        void* __restrict__ Cout, int N, int K, int k_begin, int k_len,
        int bm, int bn) {
    __shared__ unsigned short As[2][128 * 32];
    __shared__ unsigned short Bs[2][128 * 32];

    const int t = threadIdx.x;
    const int l = t & 63;
    const int w = t >> 6;
    const int wm = w >> 1, wn = w & 1;      // 2x2 wave grid, each wave 64x64

    f32x4 acc[4][4] = {};

    const size_t a_base = (size_t)bm * 128 * K;
    const size_t b_base = (size_t)bn * 128 * K;
    const int lk = (l >> 4) * 8;            // k-offset within BK=32
    const int lr = l & 15;

    // async global -> LDS staging, 16B/lane, linear LDS layout [row][32]
    auto stage = [&](int b, int k0) {
#pragma unroll
        for (int i = 0; i < 2; ++i) {
            const int idx = i * 256 + t;    // covers 8 bf16 each
            const int row = idx >> 2;
            const int col = (idx & 3) * 8;
            __builtin_amdgcn_global_load_lds(
                (const __attribute__((address_space(1))) void*)(A + a_base + (size_t)row * K + k0 + col),
                (__attribute__((address_space(3))) void*)(&As[b][idx * 8]), 16, 0, 0);
            __builtin_amdgcn_global_load_lds(
                (const __attribute__((address_space(1))) void*)(Bt + b_base + (size_t)row * K + k0 + col),
                (__attribute__((address_space(3))) void*)(&Bs[b][idx * 8]), 16, 0, 0);
        }
    };

    const int k_end = k_begin + k_len;
    stage(0, k_begin);
    __syncthreads();                        // drains vmcnt(0): buf0 ready

    int cur = 0;
    for (int k0 = k_begin; k0 < k_end; k0 += 32) {
        if (k0 + 32 < k_end) stage(cur ^ 1, k0 + 32);   // prefetch overlaps compute below
        bf16x8 af[4], bfr[4];
#pragma unroll
        for (int m = 0; m < 4; ++m)
            af[m] = *(const bf16x8*)&As[cur][(wm * 64 + m * 16 + lr) * 32 + lk];
#pragma unroll
        for (int n = 0; n < 4; ++n)
            bfr[n] = *(const bf16x8*)&Bs[cur][(wn * 64 + n * 16 + lr) * 32 + lk];
#pragma unroll
        for (int m = 0; m < 4; ++m)
#pragma unroll
            for (int n = 0; n < 4; ++n)
                acc[m][n] = __builtin_amdgcn_mfma_f32_16x16x32_bf16(af[m], bfr[n], acc[m][n], 0, 0, 0);
        __syncthreads();                    // drains prefetch vmcnt + lgkm; next buf ready
        cur ^= 1;
    }

    // epilogue: C/D layout col = lane&15, row = (lane>>4)*4 + r
    const int r0 = (l >> 4) * 4;
    const int cc = l & 15;
#pragma unroll
    for (int m = 0; m < 4; ++m) {
        const int growb = bm * 128 + wm * 64 + m * 16 + r0;
        if (MODE == 1) {
            float rs[4] = {0.f, 0.f, 0.f, 0.f};
#pragma unroll
            for (int n = 0; n < 4; ++n) {
                const int gcol = bn * 128 + wn * 64 + n * 16 + cc;
#pragma unroll
                for (int r = 0; r < 4; ++r) {
                    float e = __expf(acc[m][n][r] * (1.0f / 1024.0f));
                    rs[r] += e;
                    ((unsigned short*)Cout)[(size_t)(growb + r) * N + gcol] = f2bf(e);
                }
            }
#pragma unroll
            for (int r = 0; r < 4; ++r) {
                float v = rs[r];
                v += __shfl_xor(v, 1, 64);
                v += __shfl_xor(v, 2, 64);
                v += __shfl_xor(v, 4, 64);
                v += __shfl_xor(v, 8, 64);
                if (cc == 0) atomicAdd(&rowsum[growb + r], v);
            }
        } else {
#pragma unroll
            for (int n = 0; n < 4; ++n) {
                const int gcol = bn * 128 + wn * 64 + n * 16 + cc;
#pragma unroll
                for (int r = 0; r < 4; ++r) {
                    float v = acc[m][n][r];
                    if (MODE == 0) {
                        v += bias[gcol];
                        ((unsigned short*)Cout)[(size_t)(growb + r) * N + gcol] = f2bf(v);
                    } else {
                        atomicAdd(&((float*)Cout)[(size_t)(growb + r) * N + gcol], v);
                    }
                }
            }
        }
    }
}

// 3 projections in one dispatch: z selects (X, Wt, bias, C). 768 blocks = 3/CU.
__global__ __launch_bounds__(256) void proj3(
        const unsigned short* __restrict__ Xq, const unsigned short* __restrict__ Xk,
        const unsigned short* __restrict__ Xv,
        const unsigned short* __restrict__ Wqt, const unsigned short* __restrict__ Wkt,
        const unsigned short* __restrict__ Wvt,
        const float* __restrict__ bq, const float* __restrict__ bk, const float* __restrict__ bv,
        unsigned short* __restrict__ Qb, unsigned short* __restrict__ Kb,
        unsigned short* __restrict__ Vb) {
    const int z = blockIdx.z;
    const unsigned short* A  = (z == 0) ? Xq  : (z == 1) ? Xk  : Xv;
    const unsigned short* Bt = (z == 0) ? Wqt : (z == 1) ? Wkt : Wvt;
    const float* bias        = (z == 0) ? bq  : (z == 1) ? bk  : bv;
    unsigned short* C        = (z == 0) ? Qb  : (z == 1) ? Kb  : Vb;
    gemm_core<0>(A, Bt, bias, nullptr, C, DD, DD, 0, DD, blockIdx.y, blockIdx.x);
}

// scores + exp + rowsum: 1024 blocks = 4/CU.
__global__ __launch_bounds__(256) void gemm_scores(
        const unsigned short* __restrict__ Qb, const unsigned short* __restrict__ Kb,
        float* __restrict__ rowsum, unsigned short* __restrict__ E) {
    gemm_core<1>(Qb, Kb, nullptr, rowsum, E, SS, DD, 0, DD, blockIdx.y, blockIdx.x);
}

// out = E @ Vst^T, split-K=2 (z = K-half), atomic fp32 accumulate. 512 blocks = 2/CU.
__global__ __launch_bounds__(256) void gemm_out(
        const unsigned short* __restrict__ E, const unsigned short* __restrict__ Vst,
        float* __restrict__ out) {
    gemm_core<3>(E, Vst, nullptr, nullptr, out, DD, SS, blockIdx.z * (SS / 2), SS / 2,
                 blockIdx.y, blockIdx.x);
}

extern "C" void kernel_launch(void* const* d_in, const int* in_sizes, int n_in,
                              void* d_out, int out_size, void* d_ws, size_t ws_size,
                              hipStream_t stream) {
    const float* query = (const float*)d_in[0];
    const float* key   = (const float*)d_in[1];
    const float* value = (const float*)d_in[2];
    const float* Wq    = (const float*)d_in[3];
    const float* bq    = (const float*)d_in[4];
    const float* Wk    = (const float*)d_in[5];
    const float* bk    = (const float*)d_in[6];
    const float* Wv    = (const float*)d_in[7];
    const float* bv    = (const float*)d_in[8];
    float* out = (float*)d_out;

    char* ws = (char*)d_ws;
    const size_t SD = (size_t)SS * DD;           // 4M elems
    const size_t DDsz = (size_t)DD * DD;         // 1M elems

    // phase-1 region [0, 32MB): X (24MB) + Wt (6MB); later overlaid by E (32MB)
    unsigned short* Xq  = (unsigned short*)ws;
    unsigned short* Xk  = Xq + SD;
    unsigned short* Xv  = Xk + SD;
    unsigned short* Wqt = Xv + SD;
    unsigned short* Wkt = Wqt + DDsz;
    unsigned short* Wvt = Wkt + DDsz;
    unsigned short* E   = (unsigned short*)ws;   // overlays X/W once they are dead
    unsigned short* Qb  = (unsigned short*)(ws + ((size_t)32 << 20));
    unsigned short* Kb  = Qb + SD;
    unsigned short* Vb  = Kb + SD;
    unsigned short* Vst = Vb + SD;
    float* rowsum = (float*)(ws + ((size_t)64 << 20));

    hipMemsetAsync(rowsum, 0, SS * sizeof(float), stream);
    hipMemsetAsync(out, 0, (size_t)SS * DD * sizeof(float), stream);  // split-K accumulator

    cast3_f32_bf16<<<dim3(SS * DD / 4 / 256, 1, 3), 256, 0, stream>>>(query, key, value, Xq, Xk, Xv);

    transpose3_w<<<dim3(32, 32, 3), dim3(32, 8), 0, stream>>>(Wq, Wk, Wv, Wqt, Wkt, Wvt);

    proj3<<<dim3(DD / 128, SS / 128, 3), 256, 0, stream>>>(Xq, Xk, Xv, Wqt, Wkt, Wvt,
                                                           bq, bk, bv, Qb, Kb, Vb);

    gemm_scores<<<dim3(SS / 128, SS / 128), 256, 0, stream>>>(Qb, Kb, rowsum, E);

    scale_transpose_v<<<dim3(DD / 32, SS / 32), dim3(32, 8), 0, stream>>>(Vb, rowsum, Vst);

    gemm_out<<<dim3(DD / 128, SS / 128, 2), 256, 0, stream>>>(E, Vst, out);
}